// Round 1
// baseline (555.239 us; speedup 1.0000x reference)
//
#include <hip/hip_runtime.h>
#include <stdint.h>

// ---------------------------------------------------------------------------
// EfficientVIM block, MI355X. Dims: B=16, C=256, H=W=64, L=4096, S=64,
// CONV_DIM=192, HID=1024. All GEMMs via mfma_f32_16x16x32_bf16 (fp32 accum).
// Residual chain (x1 -> x2 -> x3 -> out) lives in d_out (in-place updates are
// block-exclusive). Workspace ~140MB for bf16 intermediates.
// ---------------------------------------------------------------------------

typedef __attribute__((ext_vector_type(8))) short bf16x8;
typedef __attribute__((ext_vector_type(4))) float f32x4;

__device__ __forceinline__ unsigned short f2b(float f){
  union { float f; unsigned int u; } v; v.f = f;
  unsigned int r = v.u + 0x7FFFu + ((v.u >> 16) & 1u);   // RNE
  return (unsigned short)(r >> 16);
}
__device__ __forceinline__ float b2f(unsigned short h){
  union { unsigned int u; float f; } v; v.u = ((unsigned int)h) << 16;
  return v.f;
}
__device__ __forceinline__ float sigm(float x){ return 1.0f / (1.0f + __expf(-x)); }
__device__ __forceinline__ float gelu_tanh(float v){
  float u = 0.7978845608028654f * v * (1.0f + 0.044715f * v * v);
  float e = __expf(2.0f * u);                 // tanh(u) = 1 - 2/(e^{2u}+1)
  float th = 1.0f - 2.0f / (e + 1.0f);
  return 0.5f * v * (1.0f + th);
}
__device__ __forceinline__ f32x4 mfma16(bf16x8 a, bf16x8 b, f32x4 c){
  return __builtin_amdgcn_mfma_f32_16x16x32_bf16(a, b, c, 0, 0, 0);
}
__device__ __forceinline__ bf16x8 ldb8g(const unsigned short* p){
  return *reinterpret_cast<const bf16x8*>(p);
}
__device__ __forceinline__ f32x4 zero4(){ f32x4 v = {0.f, 0.f, 0.f, 0.f}; return v; }

// ---------------------------------------------------------------------------
// K0: weight conversion / transposition
__global__ __launch_bounds__(256) void k_setup(
    const float* __restrict__ w1, const float* __restrict__ w2,
    const float* __restrict__ bw, const float* __restrict__ hzw,
    const float* __restrict__ outw,
    unsigned short* __restrict__ w1b, unsigned short* __restrict__ w2b,
    unsigned short* __restrict__ bwb, float* __restrict__ hzwT,
    float* __restrict__ outwT){
  int tid = blockIdx.x * 256 + threadIdx.x;          // grid 1024 -> 262144
  if (tid < 1024 * 256){ w1b[tid] = f2b(w1[tid]); w2b[tid] = f2b(w2[tid]); }
  if (tid < 192 * 256)  bwb[tid] = f2b(bw[tid]);
  if (tid < 512 * 256){ int o = tid >> 8, c = tid & 255; hzwT[c * 512 + o] = hzw[tid]; }
  if (tid < 256 * 256){ int d = tid >> 8, o = tid & 255; outwT[o * 256 + d] = outw[tid]; }
}

// ---------------------------------------------------------------------------
// K1/K9: depthwise 3x3 conv (zero pad) -> per-channel sum/sumsq (atomics)
__global__ __launch_bounds__(256) void k_conv_stats(
    const float* __restrict__ x, const float* __restrict__ w,
    float* __restrict__ bnsum, float* __restrict__ bnsq){
  __shared__ float t[66 * 66];
  __shared__ float rs[4], rq[4];
  int bc = blockIdx.x; int c = bc & 255;
  const float* xp = x + (size_t)bc * 4096;
  int tid = threadIdx.x;
  for (int i = tid; i < 66 * 66; i += 256) t[i] = 0.f;
  __syncthreads();
  #pragma unroll
  for (int j = 0; j < 4; j++){
    int p4 = tid + j * 256;
    float4 v = reinterpret_cast<const float4*>(xp)[p4];
    int p = p4 * 4; int y = p >> 6, xx = p & 63;
    int base = (y + 1) * 66 + xx + 1;
    t[base] = v.x; t[base + 1] = v.y; t[base + 2] = v.z; t[base + 3] = v.w;
  }
  __syncthreads();
  float w0 = w[c*9+0], w1 = w[c*9+1], w2 = w[c*9+2], w3 = w[c*9+3], w4 = w[c*9+4];
  float w5 = w[c*9+5], w6 = w[c*9+6], w7 = w[c*9+7], w8 = w[c*9+8];
  float s = 0.f, q = 0.f;
  #pragma unroll
  for (int j = 0; j < 16; j++){
    int p = tid + j * 256; int y = p >> 6, xx = p & 63;
    const float* r0 = &t[y * 66 + xx];
    float v = r0[0]*w0 + r0[1]*w1 + r0[2]*w2 + r0[66]*w3 + r0[67]*w4 + r0[68]*w5
            + r0[132]*w6 + r0[133]*w7 + r0[134]*w8;
    s += v; q += v * v;
  }
  #pragma unroll
  for (int off = 32; off > 0; off >>= 1){ s += __shfl_down(s, off); q += __shfl_down(q, off); }
  if ((tid & 63) == 0){ rs[tid >> 6] = s; rq[tid >> 6] = q; }
  __syncthreads();
  if (tid == 0){
    atomicAdd(&bnsum[c], rs[0] + rs[1] + rs[2] + rs[3]);
    atomicAdd(&bnsq[c],  rq[0] + rq[1] + rq[2] + rq[3]);
  }
}

// K2/K10: x_out = (1-a)*x + a*BN(conv(x)). in==out allowed (plane LDS-staged).
__global__ __launch_bounds__(256) void k_conv_bn_blend(
    const float* __restrict__ x, const float* __restrict__ w,
    const float* __restrict__ bnsum, const float* __restrict__ bnsq,
    const float* __restrict__ g, const float* __restrict__ bb,
    const float* __restrict__ alpha, float* __restrict__ out){
  __shared__ float t[66 * 66];
  int bc = blockIdx.x; int c = bc & 255;
  const float* xp = x + (size_t)bc * 4096;
  float* op = out + (size_t)bc * 4096;
  int tid = threadIdx.x;
  for (int i = tid; i < 66 * 66; i += 256) t[i] = 0.f;
  __syncthreads();
  #pragma unroll
  for (int j = 0; j < 4; j++){
    int p4 = tid + j * 256;
    float4 v = reinterpret_cast<const float4*>(xp)[p4];
    int p = p4 * 4; int y = p >> 6, xx = p & 63;
    int base = (y + 1) * 66 + xx + 1;
    t[base] = v.x; t[base + 1] = v.y; t[base + 2] = v.z; t[base + 3] = v.w;
  }
  __syncthreads();
  float w0 = w[c*9+0], w1 = w[c*9+1], w2 = w[c*9+2], w3 = w[c*9+3], w4 = w[c*9+4];
  float w5 = w[c*9+5], w6 = w[c*9+6], w7 = w[c*9+7], w8 = w[c*9+8];
  float m  = bnsum[c] * (1.f / 65536.f);
  float var = bnsq[c] * (1.f / 65536.f) - m * m;
  float sc = rsqrtf(var + 1e-5f) * g[c];
  float bias = bb[c];
  float a = sigm(alpha[c]);
  #pragma unroll
  for (int j = 0; j < 16; j++){
    int p = tid + j * 256; int y = p >> 6, xx = p & 63;
    const float* r0 = &t[y * 66 + xx];
    float v = r0[0]*w0 + r0[1]*w1 + r0[2]*w2 + r0[66]*w3 + r0[67]*w4 + r0[68]*w5
            + r0[132]*w6 + r0[133]*w7 + r0[134]*w8;
    float xv = t[(y + 1) * 66 + xx + 1];
    op[p] = (1.f - a) * xv + a * ((v - m) * sc + bias);
  }
}

// ---------------------------------------------------------------------------
// K2b: per-pixel LayerNorm over C, writes xf (b,c,l) and xfT (b,l,c), bf16
__global__ __launch_bounds__(256) void k_ln(
    const float* __restrict__ x1, const float* __restrict__ lnw,
    const float* __restrict__ lnb, unsigned short* __restrict__ xf,
    unsigned short* __restrict__ xfT){
  __shared__ unsigned short st[256 * 256];           // [c][l] bf16, 128KB
  int b = blockIdx.x >> 4, lc = blockIdx.x & 15; int l0 = lc * 256;
  int t = threadIdx.x;
  const float* xp = x1 + ((size_t)b * 256) * 4096 + l0;
  float s = 0.f, q = 0.f;
  for (int c = 0; c < 256; c++){
    float v = xp[(size_t)c * 4096 + t];
    s += v; q += v * v;
    st[c * 256 + t] = f2b(v);
  }
  float m = s * (1.f / 256.f);
  float r = rsqrtf(q * (1.f / 256.f) - m * m + 1e-5f);
  for (int c0 = 0; c0 < 256; c0 += 8){
    unsigned short buf[8];
    #pragma unroll
    for (int k = 0; k < 8; k++){
      int c = c0 + k;
      float v = b2f(st[c * 256 + t]);
      unsigned short h = f2b((v - m) * r * lnw[c] + lnb[c]);
      xf[((size_t)(b * 256 + c)) * 4096 + l0 + t] = h;
      buf[k] = h;
    }
    *reinterpret_cast<uint4*>(&xfT[((size_t)(b * 4096 + l0 + t)) * 256 + c0]) =
        *reinterpret_cast<uint4*>(buf);
  }
}

// ---------------------------------------------------------------------------
// K3: BCdt = bcdt_w(192x256) @ xf + bias  (MFMA, operands direct from global)
__global__ __launch_bounds__(256) void k_bcdt(
    const unsigned short* __restrict__ xfT, const unsigned short* __restrict__ wb,
    const float* __restrict__ bias, unsigned short* __restrict__ outp){
  int blk = blockIdx.x; int b = blk >> 6, lt = blk & 63; int l0 = lt * 64;
  int t = threadIdx.x; int wv = t >> 6, lane = t & 63;
  int col = lane & 15, g = lane >> 4;
  f32x4 acc[3][4];
  #pragma unroll
  for (int mm = 0; mm < 3; mm++)
    #pragma unroll
    for (int nn = 0; nn < 4; nn++) acc[mm][nn] = zero4();
  for (int k = 0; k < 8; k++){
    bf16x8 av[3], bv[4];
    #pragma unroll
    for (int mm = 0; mm < 3; mm++){
      int o = (wv * 3 + mm) * 16 + col;
      av[mm] = ldb8g(&wb[(size_t)o * 256 + k * 32 + g * 8]);
    }
    #pragma unroll
    for (int nn = 0; nn < 4; nn++){
      int l = l0 + nn * 16 + col;
      bv[nn] = ldb8g(&xfT[((size_t)(b * 4096 + l)) * 256 + k * 32 + g * 8]);
    }
    #pragma unroll
    for (int mm = 0; mm < 3; mm++)
      #pragma unroll
      for (int nn = 0; nn < 4; nn++) acc[mm][nn] = mfma16(av[mm], bv[nn], acc[mm][nn]);
  }
  #pragma unroll
  for (int mm = 0; mm < 3; mm++)
    #pragma unroll
    for (int nn = 0; nn < 4; nn++)
      #pragma unroll
      for (int r = 0; r < 4; r++){
        int o = (wv * 3 + mm) * 16 + g * 4 + r;
        int l = l0 + nn * 16 + col;
        outp[((size_t)(b * 192 + o)) * 4096 + l] = f2b(acc[mm][nn][r] + bias[o]);
      }
}

// ---------------------------------------------------------------------------
// K4: depthwise conv on BCdt (192 ch) + bias; dt channels also reduce softmax
// stats (max & sumexp over the full 4096-pixel plane == softmax row).
__global__ __launch_bounds__(256) void k_conv_mid(
    const unsigned short* __restrict__ in, const float* __restrict__ w,
    const float* __restrict__ wbias, unsigned short* __restrict__ outp,
    float* __restrict__ smmax, float* __restrict__ smsum){
  __shared__ float t[66 * 66];
  __shared__ float red[8];
  int blk = blockIdx.x; int b = blk / 192, ch = blk % 192;
  const unsigned short* xp = in + (size_t)blk * 4096;
  unsigned short* op = outp + (size_t)blk * 4096;
  int tid = threadIdx.x;
  for (int i = tid; i < 66 * 66; i += 256) t[i] = 0.f;
  __syncthreads();
  #pragma unroll
  for (int j = 0; j < 2; j++){
    int p8 = tid + j * 256;
    unsigned short vv[8];
    *reinterpret_cast<uint4*>(vv) = reinterpret_cast<const uint4*>(xp)[p8];
    int p = p8 * 8; int y = p >> 6, xx = p & 63;
    int base = (y + 1) * 66 + xx + 1;
    #pragma unroll
    for (int k = 0; k < 8; k++) t[base + k] = b2f(vv[k]);
  }
  __syncthreads();
  float w0 = w[ch*9+0], w1 = w[ch*9+1], w2 = w[ch*9+2], w3 = w[ch*9+3], w4 = w[ch*9+4];
  float w5 = w[ch*9+5], w6 = w[ch*9+6], w7 = w[ch*9+7], w8 = w[ch*9+8];
  float bv = wbias[ch];
  float vloc[16];
  float mx = -1e30f;
  #pragma unroll
  for (int j = 0; j < 16; j++){
    int p = tid + j * 256; int y = p >> 6, xx = p & 63;
    const float* r0 = &t[y * 66 + xx];
    float v = r0[0]*w0 + r0[1]*w1 + r0[2]*w2 + r0[66]*w3 + r0[67]*w4 + r0[68]*w5
            + r0[132]*w6 + r0[133]*w7 + r0[134]*w8 + bv;
    unsigned short h = f2b(v);
    op[p] = h;
    float vb = b2f(h);
    vloc[j] = vb;
    mx = fmaxf(mx, vb);
  }
  if (ch >= 128){                                    // dt channel: softmax stats
    #pragma unroll
    for (int off = 32; off > 0; off >>= 1) mx = fmaxf(mx, __shfl_down(mx, off));
    if ((tid & 63) == 0) red[tid >> 6] = mx;
    __syncthreads();
    float M = fmaxf(fmaxf(red[0], red[1]), fmaxf(red[2], red[3]));
    float se = 0.f;
    #pragma unroll
    for (int j = 0; j < 16; j++) se += __expf(vloc[j] - M);
    #pragma unroll
    for (int off = 32; off > 0; off >>= 1) se += __shfl_down(se, off);
    if ((tid & 63) == 0) red[4 + (tid >> 6)] = se;
    __syncthreads();
    if (tid == 0){
      smmax[b * 64 + ch - 128] = M;
      smsum[b * 64 + ch - 128] = red[4] + red[5] + red[6] + red[7];
    }
  }
}

// K5: AB = softmax(dt) * Bm  (bf16)
__global__ __launch_bounds__(256) void k_ab(
    const unsigned short* __restrict__ bc, const float* __restrict__ smmax,
    const float* __restrict__ smsum, unsigned short* __restrict__ ab){
  int blk = blockIdx.x; int b = blk >> 6, s = blk & 63;
  const unsigned short* dt = bc + ((size_t)(b * 192 + 128 + s)) * 4096;
  const unsigned short* bm = bc + ((size_t)(b * 192 + s)) * 4096;
  unsigned short* o = ab + ((size_t)(b * 64 + s)) * 4096;
  float M = smmax[b * 64 + s];
  float inv = 1.f / smsum[b * 64 + s];
  for (int i = threadIdx.x; i < 4096; i += 256)
    o[i] = f2b(__expf(b2f(dt[i]) - M) * inv * b2f(bm[i]));
}

// K5b: CmT (b,l,s) bf16 <- Cm channels 64..127 (tile transpose via LDS)
__global__ __launch_bounds__(256) void k_cmt(
    const unsigned short* __restrict__ bc, unsigned short* __restrict__ cmt){
  __shared__ float t[64 * 65];
  int blk = blockIdx.x; int b = blk >> 6, lt = blk & 63; int l0 = lt * 64;
  int tid = threadIdx.x;
  #pragma unroll
  for (int it = 0; it < 2; it++){
    int row = (tid >> 3) + it * 32;                  // s
    int lq = (tid & 7) * 8;
    const unsigned short* p = bc + ((size_t)(b * 192 + 64 + row)) * 4096 + l0 + lq;
    unsigned short vv[8];
    *reinterpret_cast<uint4*>(vv) = *reinterpret_cast<const uint4*>(p);
    #pragma unroll
    for (int k = 0; k < 8; k++) t[row * 65 + lq + k] = b2f(vv[k]);
  }
  __syncthreads();
  #pragma unroll
  for (int it = 0; it < 2; it++){
    int l = (tid >> 3) + it * 32;
    int sq = (tid & 7) * 8;
    unsigned short vv[8];
    #pragma unroll
    for (int k = 0; k < 8; k++) vv[k] = f2b(t[(sq + k) * 65 + l]);
    *reinterpret_cast<uint4*>(&cmt[((size_t)(b * 4096 + l0 + l)) * 64 + sq]) =
        *reinterpret_cast<uint4*>(vv);
  }
}

// ---------------------------------------------------------------------------
// K6: hT[b,s,c] += sum_l AB[s,l]*xf[c,l]  -- k-split over l, partials in ws
__global__ __launch_bounds__(512) void k_h(
    const unsigned short* __restrict__ ab, const unsigned short* __restrict__ xf,
    float* __restrict__ hpart){
  int blk = blockIdx.x; int b = blk & 15, chunk = blk >> 4;   // grid 128
  int t = threadIdx.x; int wv = t >> 6, lane = t & 63;
  int col = lane & 15, g = lane >> 4;
  int mt = wv & 3, nh = wv >> 2;
  f32x4 acc[8];
  #pragma unroll
  for (int nn = 0; nn < 8; nn++) acc[nn] = zero4();
  int lbase = chunk * 512;
  const unsigned short* ap = ab + ((size_t)(b * 64 + mt * 16 + col)) * 4096 + lbase + g * 8;
  for (int ks = 0; ks < 16; ks++){
    bf16x8 av = ldb8g(ap + ks * 32);
    #pragma unroll
    for (int nn = 0; nn < 8; nn++){
      int c = nh * 128 + nn * 16 + col;
      bf16x8 bv = ldb8g(&xf[((size_t)(b * 256 + c)) * 4096 + lbase + ks * 32 + g * 8]);
      acc[nn] = mfma16(av, bv, acc[nn]);
    }
  }
  #pragma unroll
  for (int nn = 0; nn < 8; nn++)
    #pragma unroll
    for (int r = 0; r < 4; r++){
      int s = mt * 16 + g * 4 + r;
      int c = nh * 128 + nn * 16 + col;
      hpart[(((size_t)chunk * 16 + b) * 64 + s) * 256 + c] = acc[nn][r];
    }
}

// K7pre: sum 8 k-partials
__global__ __launch_bounds__(256) void k_hsum(
    const float* __restrict__ hp, float* __restrict__ hs){
  int i = blockIdx.x * 256 + threadIdx.x;            // 262144
  float s = 0.f;
  #pragma unroll
  for (int c = 0; c < 8; c++) s += hp[(size_t)c * 262144 + i];
  hs[i] = s;
}

// K7a: u = hz_w @ h + hz_b ; hh1 = u_lo * (silu(u_hi) + D)   layout (b,s,o)
__global__ __launch_bounds__(256) void k_hz(
    const float* __restrict__ hs, const float* __restrict__ hzwT,
    const float* __restrict__ hzb, const float* __restrict__ Dp,
    float* __restrict__ hh1){
  __shared__ float ht[256][16];
  int blk = blockIdx.x; int b = blk >> 2, sc = blk & 3; int s0 = sc * 16;
  int t = threadIdx.x;
  {
    int si = t >> 4, c0 = (t & 15) * 16;
    const float* p = hs + ((size_t)(b * 64 + s0 + si)) * 256 + c0;
    #pragma unroll
    for (int k = 0; k < 16; k++) ht[c0 + k][si] = p[k];
  }
  __syncthreads();
  float Dv = Dp[0];
  float acc1[16], acc2[16];
  #pragma unroll
  for (int j = 0; j < 16; j++){ acc1[j] = 0.f; acc2[j] = 0.f; }
  for (int c = 0; c < 256; c++){
    float w1 = hzwT[c * 512 + t];
    float w2 = hzwT[c * 512 + 256 + t];
    float4 h0 = *reinterpret_cast<const float4*>(&ht[c][0]);
    float4 h1 = *reinterpret_cast<const float4*>(&ht[c][4]);
    float4 h2 = *reinterpret_cast<const float4*>(&ht[c][8]);
    float4 h3 = *reinterpret_cast<const float4*>(&ht[c][12]);
    float hv[16] = {h0.x,h0.y,h0.z,h0.w, h1.x,h1.y,h1.z,h1.w,
                    h2.x,h2.y,h2.z,h2.w, h3.x,h3.y,h3.z,h3.w};
    #pragma unroll
    for (int j = 0; j < 16; j++){ acc1[j] += w1 * hv[j]; acc2[j] += w2 * hv[j]; }
  }
  float bz1 = hzb[t], bz2 = hzb[256 + t];
  #pragma unroll
  for (int j = 0; j < 16; j++){
    float u = acc1[j] + bz1, z = acc2[j] + bz2;
    float sl = z / (1.f + __expf(-z));
    hh1[((size_t)(b * 64 + s0 + j)) * 256 + t] = u * (sl + Dv);
  }
}

// K7b: hh2 = out_w @ hh1 + out_b   -> bf16 (b,d,s)
__global__ __launch_bounds__(256) void k_out(
    const float* __restrict__ hh1, const float* __restrict__ outwT,
    const float* __restrict__ ob, unsigned short* __restrict__ hh2){
  __shared__ float ht[256][16];
  int blk = blockIdx.x; int b = blk >> 2, sc = blk & 3; int s0 = sc * 16;
  int t = threadIdx.x;
  {
    int si = t >> 4, o0 = (t & 15) * 16;
    const float* p = hh1 + ((size_t)(b * 64 + s0 + si)) * 256 + o0;
    #pragma unroll
    for (int k = 0; k < 16; k++) ht[o0 + k][si] = p[k];
  }
  __syncthreads();
  float acc[16];
  #pragma unroll
  for (int j = 0; j < 16; j++) acc[j] = 0.f;
  for (int o = 0; o < 256; o++){
    float w = outwT[o * 256 + t];
    float4 h0 = *reinterpret_cast<const float4*>(&ht[o][0]);
    float4 h1 = *reinterpret_cast<const float4*>(&ht[o][4]);
    float4 h2 = *reinterpret_cast<const float4*>(&ht[o][8]);
    float4 h3 = *reinterpret_cast<const float4*>(&ht[o][12]);
    float hv[16] = {h0.x,h0.y,h0.z,h0.w, h1.x,h1.y,h1.z,h1.w,
                    h2.x,h2.y,h2.z,h2.w, h3.x,h3.y,h3.z,h3.w};
    #pragma unroll
    for (int j = 0; j < 16; j++) acc[j] += w * hv[j];
  }
  float bo = ob[t];
  #pragma unroll
  for (int j = 0; j < 16; j++)
    hh2[((size_t)(b * 256 + t)) * 64 + s0 + j] = f2b(acc[j] + bo);
}

// K8: y = hh2 @ Cm ; x2 = (1-a1)*x1 + a1*y  (in-place on d_out)
__global__ __launch_bounds__(256) void k_y_blend(
    const unsigned short* __restrict__ hh2, const unsigned short* __restrict__ cmt,
    const float* __restrict__ alpha, float* __restrict__ x){
  int blk = blockIdx.x; int b = blk >> 6, lt = blk & 63; int l0 = lt * 64;
  int t = threadIdx.x; int wv = t >> 6, lane = t & 63;
  int col = lane & 15, g = lane >> 4;
  f32x4 acc[4][4];
  #pragma unroll
  for (int mm = 0; mm < 4; mm++)
    #pragma unroll
    for (int nn = 0; nn < 4; nn++) acc[mm][nn] = zero4();
  #pragma unroll
  for (int k = 0; k < 2; k++){
    bf16x8 av[4], bv[4];
    #pragma unroll
    for (int mm = 0; mm < 4; mm++){
      int c = (wv * 4 + mm) * 16 + col;
      av[mm] = ldb8g(&hh2[((size_t)(b * 256 + c)) * 64 + k * 32 + g * 8]);
    }
    #pragma unroll
    for (int nn = 0; nn < 4; nn++){
      int l = l0 + nn * 16 + col;
      bv[nn] = ldb8g(&cmt[((size_t)(b * 4096 + l)) * 64 + k * 32 + g * 8]);
    }
    #pragma unroll
    for (int mm = 0; mm < 4; mm++)
      #pragma unroll
      for (int nn = 0; nn < 4; nn++) acc[mm][nn] = mfma16(av[mm], bv[nn], acc[mm][nn]);
  }
  #pragma unroll
  for (int mm = 0; mm < 4; mm++)
    #pragma unroll
    for (int r = 0; r < 4; r++){
      int c = (wv * 4 + mm) * 16 + g * 4 + r;
      float a1 = sigm(alpha[c]);
      #pragma unroll
      for (int nn = 0; nn < 4; nn++){
        int l = l0 + nn * 16 + col;
        size_t idx = ((size_t)(b * 256 + c)) * 4096 + l;
        float xv = x[idx];
        x[idx] = (1.f - a1) * xv + a1 * acc[mm][nn][r];
      }
    }
}

// ---------------------------------------------------------------------------
// K11: fused FFN: out = (1-a3)*x3 + a3*(W2 @ gelu(W1 @ x3 + b1) + b2), in-place
// Block: 128 pixels, 512 threads. XT (128x256 bf16) + HT (128x256 bf16 per
// o-quarter) in LDS; stage-2 accumulators persist in registers across quarters.
__global__ __launch_bounds__(512) void k_ffn(
    float* __restrict__ x, const unsigned short* __restrict__ w1b,
    const unsigned short* __restrict__ w2b, const float* __restrict__ b1,
    const float* __restrict__ b2, const float* __restrict__ alpha3){
  __shared__ unsigned short XT[128 * 264];
  __shared__ unsigned short HT[128 * 264];
  __shared__ float tmp[32 * 132];
  int blk = blockIdx.x; int b = blk >> 5, lt = blk & 31; int l0 = lt * 128;
  int t = threadIdx.x, wv = t >> 6, lane = t & 63;
  int col = lane & 15, g = lane >> 4;
  const float* xbase = x + ((size_t)b * 256) * 4096 + l0;
  // stage XT via fp32 LDS chunks (coalesced global, conflict-light transpose)
  for (int ch = 0; ch < 8; ch++){
    #pragma unroll
    for (int j = 0; j < 2; j++){
      int f4 = t + j * 512;
      int c = f4 >> 5, l4 = f4 & 31;
      float4 v = *reinterpret_cast<const float4*>(&xbase[(size_t)(ch * 32 + c) * 4096 + l4 * 4]);
      float* dst = &tmp[c * 132 + l4 * 4];
      dst[0] = v.x; dst[1] = v.y; dst[2] = v.z; dst[3] = v.w;
    }
    __syncthreads();
    {
      int l = t & 127, oc = t >> 7;
      unsigned short h8[8];
      #pragma unroll
      for (int k = 0; k < 8; k++) h8[k] = f2b(tmp[(oc * 8 + k) * 132 + l]);
      *reinterpret_cast<uint4*>(&XT[l * 264 + ch * 32 + oc * 8]) =
          *reinterpret_cast<uint4*>(h8);
    }
    __syncthreads();
  }
  f32x4 acc2[2][8];
  #pragma unroll
  for (int i = 0; i < 2; i++)
    #pragma unroll
    for (int nn = 0; nn < 8; nn++) acc2[i][nn] = zero4();
  for (int q = 0; q < 4; q++){
    int obq = q * 256;
    f32x4 acc1[2][8];
    #pragma unroll
    for (int i = 0; i < 2; i++)
      #pragma unroll
      for (int nn = 0; nn < 8; nn++) acc1[i][nn] = zero4();
    for (int k = 0; k < 8; k++){
      bf16x8 bv[8];
      #pragma unroll
      for (int nn = 0; nn < 8; nn++)
        bv[nn] = *reinterpret_cast<const bf16x8*>(&XT[(nn * 16 + col) * 264 + k * 32 + g * 8]);
      #pragma unroll
      for (int i = 0; i < 2; i++){
        int o = obq + (wv * 2 + i) * 16 + col;
        bf16x8 av = ldb8g(&w1b[(size_t)o * 256 + k * 32 + g * 8]);
        #pragma unroll
        for (int nn = 0; nn < 8; nn++) acc1[i][nn] = mfma16(av, bv[nn], acc1[i][nn]);
      }
    }
    // gelu + write HT (bf16, [l][o_quarter])
    #pragma unroll
    for (int i = 0; i < 2; i++){
      int orow0 = (wv * 2 + i) * 16 + g * 4;
      #pragma unroll
      for (int nn = 0; nn < 8; nn++){
        int l = nn * 16 + col;
        unsigned short hv[4];
        #pragma unroll
        for (int r = 0; r < 4; r++){
          float u = acc1[i][nn][r] + b1[obq + orow0 + r];
          hv[r] = f2b(gelu_tanh(u));
        }
        *reinterpret_cast<uint2*>(&HT[l * 264 + orow0]) = *reinterpret_cast<uint2*>(hv);
      }
    }
    __syncthreads();
    for (int k = 0; k < 8; k++){
      bf16x8 bv[8];
      #pragma unroll
      for (int nn = 0; nn < 8; nn++)
        bv[nn] = *reinterpret_cast<const bf16x8*>(&HT[(nn * 16 + col) * 264 + k * 32 + g * 8]);
      #pragma unroll
      for (int i = 0; i < 2; i++){
        int d = (wv * 2 + i) * 16 + col;
        bf16x8 av = ldb8g(&w2b[(size_t)d * 1024 + obq + k * 32 + g * 8]);
        #pragma unroll
        for (int nn = 0; nn < 8; nn++) acc2[i][nn] = mfma16(av, bv[nn], acc2[i][nn]);
      }
    }
    __syncthreads();
  }
  #pragma unroll
  for (int i = 0; i < 2; i++)
    #pragma unroll
    for (int nn = 0; nn < 8; nn++)
      #pragma unroll
      for (int r = 0; r < 4; r++){
        int d = (wv * 2 + i) * 16 + g * 4 + r;
        int l = l0 + nn * 16 + col;
        float a3 = sigm(alpha3[d]);
        size_t idx = ((size_t)(b * 256 + d)) * 4096 + l;
        float xv = x[idx];
        x[idx] = (1.f - a3) * xv + a3 * (acc2[i][nn][r] + b2[d]);
      }
}

// ---------------------------------------------------------------------------
extern "C" void kernel_launch(void* const* d_in, const int* in_sizes, int n_in,
                              void* d_out, int out_size, void* d_ws, size_t ws_size,
                              hipStream_t stream){
  (void)in_sizes; (void)n_in; (void)out_size; (void)ws_size;
  const float* x      = (const float*)d_in[0];
  const float* alpha  = (const float*)d_in[1];
  const float* dw1_w  = (const float*)d_in[2];
  const float* bn1_g  = (const float*)d_in[3];
  const float* bn1_b  = (const float*)d_in[4];
  const float* dw2_w  = (const float*)d_in[5];
  const float* bn2_g  = (const float*)d_in[6];
  const float* bn2_b  = (const float*)d_in[7];
  const float* ln_w   = (const float*)d_in[8];
  const float* ln_b   = (const float*)d_in[9];
  const float* bcdt_w = (const float*)d_in[10];
  const float* bcdt_b = (const float*)d_in[11];
  const float* mdw_w  = (const float*)d_in[12];
  const float* mdw_b  = (const float*)d_in[13];
  const float* hz_w   = (const float*)d_in[14];
  const float* hz_b   = (const float*)d_in[15];
  const float* out_w  = (const float*)d_in[16];
  const float* out_b  = (const float*)d_in[17];
  // d_in[18] = A: cancels exactly in softmax over L (constant shift per row)
  const float* Dvec   = (const float*)d_in[19];
  const float* ffn_w1 = (const float*)d_in[20];
  const float* ffn_b1 = (const float*)d_in[21];
  const float* ffn_w2 = (const float*)d_in[22];
  const float* ffn_b2 = (const float*)d_in[23];
  float* out = (float*)d_out;
  char* ws = (char*)d_ws;

  const size_t OFF_BCRAW = 0;                    // 16*192*4096*2 = 25165824
  const size_t OFF_BCC   = 25165824;             // 25165824
  const size_t OFF_XF    = 50331648;             // 33554432
  const size_t OFF_XFT   = 83886080;             // 33554432
  const size_t OFF_AB    = 117440512;            // 8388608
  const size_t OFF_CMT   = 125829120;            // 8388608
  const size_t OFF_HPART = 134217728;            // 8388608
  const size_t OFF_HS    = 142606336;            // 1048576
  const size_t OFF_HH1   = 143654912;            // 1048576
  const size_t OFF_HH2   = 144703488;            // 524288
  const size_t OFF_W1B   = 145227776;            // 524288
  const size_t OFF_W2B   = 145752064;            // 524288
  const size_t OFF_BWB   = 146276352;            // 98304
  const size_t OFF_HZWT  = 146374656;            // 524288
  const size_t OFF_OUTWT = 146898944;            // 262144
  const size_t OFF_STATS = 147161088;            // 4096: bn1sum,bn1sq,bn2sum,bn2sq
  const size_t OFF_SMMAX = 147165184;            // 4096
  const size_t OFF_SMSUM = 147169280;            // 4096

  unsigned short* bcraw = (unsigned short*)(ws + OFF_BCRAW);
  unsigned short* bcc   = (unsigned short*)(ws + OFF_BCC);
  unsigned short* xf    = (unsigned short*)(ws + OFF_XF);
  unsigned short* xfT   = (unsigned short*)(ws + OFF_XFT);
  unsigned short* ab    = (unsigned short*)(ws + OFF_AB);
  unsigned short* cmt   = (unsigned short*)(ws + OFF_CMT);
  float* hpart = (float*)(ws + OFF_HPART);
  float* hs    = (float*)(ws + OFF_HS);
  float* hh1   = (float*)(ws + OFF_HH1);
  unsigned short* hh2 = (unsigned short*)(ws + OFF_HH2);
  unsigned short* w1b = (unsigned short*)(ws + OFF_W1B);
  unsigned short* w2b = (unsigned short*)(ws + OFF_W2B);
  unsigned short* bwb = (unsigned short*)(ws + OFF_BWB);
  float* hzwT  = (float*)(ws + OFF_HZWT);
  float* outwT = (float*)(ws + OFF_OUTWT);
  float* bn1sum = (float*)(ws + OFF_STATS);
  float* bn1sq  = bn1sum + 256;
  float* bn2sum = bn1sum + 512;
  float* bn2sq  = bn1sum + 768;
  float* smmax = (float*)(ws + OFF_SMMAX);
  float* smsum = (float*)(ws + OFF_SMSUM);

  hipMemsetAsync(ws + OFF_STATS, 0, 4096, stream);
  k_setup<<<1024, 256, 0, stream>>>(ffn_w1, ffn_w2, bcdt_w, hz_w, out_w,
                                    w1b, w2b, bwb, hzwT, outwT);
  // stage 1: x1 = blend(x, BN(conv(x))), into d_out
  k_conv_stats<<<4096, 256, 0, stream>>>(x, dw1_w, bn1sum, bn1sq);
  k_conv_bn_blend<<<4096, 256, 0, stream>>>(x, dw1_w, bn1sum, bn1sq,
                                            bn1_g, bn1_b, alpha + 0, out);
  // LN -> xf/xfT bf16
  k_ln<<<256, 256, 0, stream>>>(out, ln_w, ln_b, xf, xfT);
  // mixer
  k_bcdt<<<1024, 256, 0, stream>>>(xfT, bwb, bcdt_b, bcraw);
  k_conv_mid<<<3072, 256, 0, stream>>>(bcraw, mdw_w, mdw_b, bcc, smmax, smsum);
  k_ab<<<1024, 256, 0, stream>>>(bcc, smmax, smsum, ab);
  k_cmt<<<1024, 256, 0, stream>>>(bcc, cmt);
  k_h<<<128, 512, 0, stream>>>(ab, xf, hpart);
  k_hsum<<<1024, 256, 0, stream>>>(hpart, hs);
  k_hz<<<64, 256, 0, stream>>>(hs, hzwT, hz_b, Dvec, hh1);
  k_out<<<64, 256, 0, stream>>>(hh1, outwT, out_b, hh2);
  k_y_blend<<<1024, 256, 0, stream>>>(hh2, cmt, alpha + 256, out);
  // stage 2: x3 = blend(x2, BN2(conv2(x2))), in-place on d_out
  k_conv_stats<<<4096, 256, 0, stream>>>(out, dw2_w, bn2sum, bn2sq);
  k_conv_bn_blend<<<4096, 256, 0, stream>>>(out, dw2_w, bn2sum, bn2sq,
                                            bn2_g, bn2_b, alpha + 512, out);
  // fused FFN + final blend, in-place on d_out
  k_ffn<<<512, 512, 0, stream>>>(out, w1b, w2b, ffn_b1, ffn_b2, alpha + 768);
}

// Round 2
// 522.144 us; speedup vs baseline: 1.0634x; 1.0634x over previous
//
#include <hip/hip_runtime.h>
#include <stdint.h>

// ---------------------------------------------------------------------------
// EfficientVIM block, MI355X. Dims: B=16, C=256, H=W=64, L=4096, S=64,
// CONV_DIM=192, HID=1024. All GEMMs via mfma_f32_16x16x32_bf16 (fp32 accum).
// Residual chain (x1 -> x2 -> x3 -> out) lives in d_out.
// R1: k_ffn rebuilt for 2 blocks/CU (66KB LDS, pre-transposed X); k_ln rebuilt
// for 4 blocks/CU; new k_xt transpose feeding k_ffn.
// ---------------------------------------------------------------------------

typedef __attribute__((ext_vector_type(8))) short bf16x8;
typedef __attribute__((ext_vector_type(4))) float f32x4;

__device__ __forceinline__ unsigned short f2b(float f){
  union { float f; unsigned int u; } v; v.f = f;
  unsigned int r = v.u + 0x7FFFu + ((v.u >> 16) & 1u);   // RNE
  return (unsigned short)(r >> 16);
}
__device__ __forceinline__ float b2f(unsigned short h){
  union { unsigned int u; float f; } v; v.u = ((unsigned int)h) << 16;
  return v.f;
}
__device__ __forceinline__ float sigm(float x){ return 1.0f / (1.0f + __expf(-x)); }
__device__ __forceinline__ float gelu_tanh(float v){
  float u = 0.7978845608028654f * v * (1.0f + 0.044715f * v * v);
  float e = __expf(2.0f * u);                 // tanh(u) = 1 - 2/(e^{2u}+1)
  float th = 1.0f - 2.0f / (e + 1.0f);
  return 0.5f * v * (1.0f + th);
}
__device__ __forceinline__ f32x4 mfma16(bf16x8 a, bf16x8 b, f32x4 c){
  return __builtin_amdgcn_mfma_f32_16x16x32_bf16(a, b, c, 0, 0, 0);
}
__device__ __forceinline__ bf16x8 ldb8g(const unsigned short* p){
  return *reinterpret_cast<const bf16x8*>(p);
}
__device__ __forceinline__ f32x4 zero4(){ f32x4 v = {0.f, 0.f, 0.f, 0.f}; return v; }

// ---------------------------------------------------------------------------
// K0: weight conversion / transposition
__global__ __launch_bounds__(256) void k_setup(
    const float* __restrict__ w1, const float* __restrict__ w2,
    const float* __restrict__ bw, const float* __restrict__ hzw,
    const float* __restrict__ outw,
    unsigned short* __restrict__ w1b, unsigned short* __restrict__ w2b,
    unsigned short* __restrict__ bwb, float* __restrict__ hzwT,
    float* __restrict__ outwT){
  int tid = blockIdx.x * 256 + threadIdx.x;          // grid 1024 -> 262144
  if (tid < 1024 * 256){ w1b[tid] = f2b(w1[tid]); w2b[tid] = f2b(w2[tid]); }
  if (tid < 192 * 256)  bwb[tid] = f2b(bw[tid]);
  if (tid < 512 * 256){ int o = tid >> 8, c = tid & 255; hzwT[c * 512 + o] = hzw[tid]; }
  if (tid < 256 * 256){ int d = tid >> 8, o = tid & 255; outwT[o * 256 + d] = outw[tid]; }
}

// ---------------------------------------------------------------------------
// K1/K9: depthwise 3x3 conv (zero pad) -> per-channel sum/sumsq (atomics)
__global__ __launch_bounds__(256) void k_conv_stats(
    const float* __restrict__ x, const float* __restrict__ w,
    float* __restrict__ bnsum, float* __restrict__ bnsq){
  __shared__ float t[66 * 66];
  __shared__ float rs[4], rq[4];
  int bc = blockIdx.x; int c = bc & 255;
  const float* xp = x + (size_t)bc * 4096;
  int tid = threadIdx.x;
  for (int i = tid; i < 66 * 66; i += 256) t[i] = 0.f;
  __syncthreads();
  #pragma unroll
  for (int j = 0; j < 4; j++){
    int p4 = tid + j * 256;
    float4 v = reinterpret_cast<const float4*>(xp)[p4];
    int p = p4 * 4; int y = p >> 6, xx = p & 63;
    int base = (y + 1) * 66 + xx + 1;
    t[base] = v.x; t[base + 1] = v.y; t[base + 2] = v.z; t[base + 3] = v.w;
  }
  __syncthreads();
  float w0 = w[c*9+0], w1 = w[c*9+1], w2 = w[c*9+2], w3 = w[c*9+3], w4 = w[c*9+4];
  float w5 = w[c*9+5], w6 = w[c*9+6], w7 = w[c*9+7], w8 = w[c*9+8];
  float s = 0.f, q = 0.f;
  #pragma unroll
  for (int j = 0; j < 16; j++){
    int p = tid + j * 256; int y = p >> 6, xx = p & 63;
    const float* r0 = &t[y * 66 + xx];
    float v = r0[0]*w0 + r0[1]*w1 + r0[2]*w2 + r0[66]*w3 + r0[67]*w4 + r0[68]*w5
            + r0[132]*w6 + r0[133]*w7 + r0[134]*w8;
    s += v; q += v * v;
  }
  #pragma unroll
  for (int off = 32; off > 0; off >>= 1){ s += __shfl_down(s, off); q += __shfl_down(q, off); }
  if ((tid & 63) == 0){ rs[tid >> 6] = s; rq[tid >> 6] = q; }
  __syncthreads();
  if (tid == 0){
    atomicAdd(&bnsum[c], rs[0] + rs[1] + rs[2] + rs[3]);
    atomicAdd(&bnsq[c],  rq[0] + rq[1] + rq[2] + rq[3]);
  }
}

// K2/K10: x_out = (1-a)*x + a*BN(conv(x)). in==out allowed (plane LDS-staged).
__global__ __launch_bounds__(256) void k_conv_bn_blend(
    const float* __restrict__ x, const float* __restrict__ w,
    const float* __restrict__ bnsum, const float* __restrict__ bnsq,
    const float* __restrict__ g, const float* __restrict__ bb,
    const float* __restrict__ alpha, float* __restrict__ out){
  __shared__ float t[66 * 66];
  int bc = blockIdx.x; int c = bc & 255;
  const float* xp = x + (size_t)bc * 4096;
  float* op = out + (size_t)bc * 4096;
  int tid = threadIdx.x;
  for (int i = tid; i < 66 * 66; i += 256) t[i] = 0.f;
  __syncthreads();
  #pragma unroll
  for (int j = 0; j < 4; j++){
    int p4 = tid + j * 256;
    float4 v = reinterpret_cast<const float4*>(xp)[p4];
    int p = p4 * 4; int y = p >> 6, xx = p & 63;
    int base = (y + 1) * 66 + xx + 1;
    t[base] = v.x; t[base + 1] = v.y; t[base + 2] = v.z; t[base + 3] = v.w;
  }
  __syncthreads();
  float w0 = w[c*9+0], w1 = w[c*9+1], w2 = w[c*9+2], w3 = w[c*9+3], w4 = w[c*9+4];
  float w5 = w[c*9+5], w6 = w[c*9+6], w7 = w[c*9+7], w8 = w[c*9+8];
  float m  = bnsum[c] * (1.f / 65536.f);
  float var = bnsq[c] * (1.f / 65536.f) - m * m;
  float sc = rsqrtf(var + 1e-5f) * g[c];
  float bias = bb[c];
  float a = sigm(alpha[c]);
  #pragma unroll
  for (int j = 0; j < 16; j++){
    int p = tid + j * 256; int y = p >> 6, xx = p & 63;
    const float* r0 = &t[y * 66 + xx];
    float v = r0[0]*w0 + r0[1]*w1 + r0[2]*w2 + r0[66]*w3 + r0[67]*w4 + r0[68]*w5
            + r0[132]*w6 + r0[133]*w7 + r0[134]*w8;
    float xv = t[(y + 1) * 66 + xx + 1];
    op[p] = (1.f - a) * xv + a * ((v - m) * sc + bias);
  }
}

// ---------------------------------------------------------------------------
// K2b: per-pixel LayerNorm over C -> xf (b,c,l) and xfT (b,l,c), bf16.
// 64-pixel tile, 4 waves each covering 64 channels; 33KB LDS -> 4 blocks/CU.
__global__ __launch_bounds__(256) void k_ln(
    const float* __restrict__ x1, const float* __restrict__ lnw,
    const float* __restrict__ lnb, unsigned short* __restrict__ xf,
    unsigned short* __restrict__ xfT){
  __shared__ unsigned short st[256 * 65];            // [c][pixel], pad 65
  __shared__ float reds[4][64], redq[4][64];
  int b = blockIdx.x >> 6, lt = blockIdx.x & 63; int l0 = lt * 64;
  int t = threadIdx.x, w = t >> 6, lane = t & 63;
  const float* xp = x1 + ((size_t)b * 256) * 4096 + l0 + lane;
  float s = 0.f, q = 0.f;
  for (int i = 0; i < 64; i++){
    int c = w * 64 + i;
    float v = xp[(size_t)c * 4096];
    s += v; q += v * v;
    st[c * 65 + lane] = f2b(v);
  }
  reds[w][lane] = s; redq[w][lane] = q;
  __syncthreads();
  s = reds[0][lane] + reds[1][lane] + reds[2][lane] + reds[3][lane];
  q = redq[0][lane] + redq[1][lane] + redq[2][lane] + redq[3][lane];
  float m = s * (1.f / 256.f);
  float r = rsqrtf(q * (1.f / 256.f) - m * m + 1e-5f);
  for (int i = 0; i < 64; i++){
    int c = w * 64 + i;
    float v = b2f(st[c * 65 + lane]);
    unsigned short h = f2b((v - m) * r * lnw[c] + lnb[c]);
    st[c * 65 + lane] = h;
    xf[((size_t)(b * 256 + c)) * 4096 + l0 + lane] = h;
  }
  __syncthreads();
  int p = t >> 4, cc = t & 15;                       // 16 lanes per pixel row
  for (int pi = 0; pi < 4; pi++){
    int px = p + pi * 16;
    #pragma unroll
    for (int j = 0; j < 2; j++){
      int c0 = (j * 16 + cc) * 8;
      unsigned short vv[8];
      #pragma unroll
      for (int k = 0; k < 8; k++) vv[k] = st[(c0 + k) * 65 + px];
      *reinterpret_cast<uint4*>(&xfT[((size_t)(b * 4096 + l0 + px)) * 256 + c0]) =
          *reinterpret_cast<uint4*>(vv);
    }
  }
}

// K2c: x3 fp32 (b,c,l) -> x3T bf16 (b,l,c); same tiling as k_ln.
__global__ __launch_bounds__(256) void k_xt(
    const float* __restrict__ x, unsigned short* __restrict__ xT){
  __shared__ unsigned short st[256 * 65];
  int b = blockIdx.x >> 6, lt = blockIdx.x & 63; int l0 = lt * 64;
  int t = threadIdx.x, w = t >> 6, lane = t & 63;
  const float* xp = x + ((size_t)b * 256) * 4096 + l0 + lane;
  for (int i = 0; i < 64; i++){
    int c = w * 64 + i;
    st[c * 65 + lane] = f2b(xp[(size_t)c * 4096]);
  }
  __syncthreads();
  int p = t >> 4, cc = t & 15;
  for (int pi = 0; pi < 4; pi++){
    int px = p + pi * 16;
    #pragma unroll
    for (int j = 0; j < 2; j++){
      int c0 = (j * 16 + cc) * 8;
      unsigned short vv[8];
      #pragma unroll
      for (int k = 0; k < 8; k++) vv[k] = st[(c0 + k) * 65 + px];
      *reinterpret_cast<uint4*>(&xT[((size_t)(b * 4096 + l0 + px)) * 256 + c0]) =
          *reinterpret_cast<uint4*>(vv);
    }
  }
}

// ---------------------------------------------------------------------------
// K3: BCdt = bcdt_w(192x256) @ xf + bias  (MFMA, operands direct from global)
__global__ __launch_bounds__(256) void k_bcdt(
    const unsigned short* __restrict__ xfT, const unsigned short* __restrict__ wb,
    const float* __restrict__ bias, unsigned short* __restrict__ outp){
  int blk = blockIdx.x; int b = blk >> 6, lt = blk & 63; int l0 = lt * 64;
  int t = threadIdx.x; int wv = t >> 6, lane = t & 63;
  int col = lane & 15, g = lane >> 4;
  f32x4 acc[3][4];
  #pragma unroll
  for (int mm = 0; mm < 3; mm++)
    #pragma unroll
    for (int nn = 0; nn < 4; nn++) acc[mm][nn] = zero4();
  for (int k = 0; k < 8; k++){
    bf16x8 av[3], bv[4];
    #pragma unroll
    for (int mm = 0; mm < 3; mm++){
      int o = (wv * 3 + mm) * 16 + col;
      av[mm] = ldb8g(&wb[(size_t)o * 256 + k * 32 + g * 8]);
    }
    #pragma unroll
    for (int nn = 0; nn < 4; nn++){
      int l = l0 + nn * 16 + col;
      bv[nn] = ldb8g(&xfT[((size_t)(b * 4096 + l)) * 256 + k * 32 + g * 8]);
    }
    #pragma unroll
    for (int mm = 0; mm < 3; mm++)
      #pragma unroll
      for (int nn = 0; nn < 4; nn++) acc[mm][nn] = mfma16(av[mm], bv[nn], acc[mm][nn]);
  }
  #pragma unroll
  for (int mm = 0; mm < 3; mm++)
    #pragma unroll
    for (int nn = 0; nn < 4; nn++)
      #pragma unroll
      for (int r = 0; r < 4; r++){
        int o = (wv * 3 + mm) * 16 + g * 4 + r;
        int l = l0 + nn * 16 + col;
        outp[((size_t)(b * 192 + o)) * 4096 + l] = f2b(acc[mm][nn][r] + bias[o]);
      }
}

// ---------------------------------------------------------------------------
// K4: depthwise conv on BCdt (192 ch) + bias; dt channels also reduce softmax
// stats (max & sumexp over the full 4096-pixel plane == softmax row).
__global__ __launch_bounds__(256) void k_conv_mid(
    const unsigned short* __restrict__ in, const float* __restrict__ w,
    const float* __restrict__ wbias, unsigned short* __restrict__ outp,
    float* __restrict__ smmax, float* __restrict__ smsum){
  __shared__ float t[66 * 66];
  __shared__ float red[8];
  int blk = blockIdx.x; int b = blk / 192, ch = blk % 192;
  const unsigned short* xp = in + (size_t)blk * 4096;
  unsigned short* op = outp + (size_t)blk * 4096;
  int tid = threadIdx.x;
  for (int i = tid; i < 66 * 66; i += 256) t[i] = 0.f;
  __syncthreads();
  #pragma unroll
  for (int j = 0; j < 2; j++){
    int p8 = tid + j * 256;
    unsigned short vv[8];
    *reinterpret_cast<uint4*>(vv) = reinterpret_cast<const uint4*>(xp)[p8];
    int p = p8 * 8; int y = p >> 6, xx = p & 63;
    int base = (y + 1) * 66 + xx + 1;
    #pragma unroll
    for (int k = 0; k < 8; k++) t[base + k] = b2f(vv[k]);
  }
  __syncthreads();
  float w0 = w[ch*9+0], w1 = w[ch*9+1], w2 = w[ch*9+2], w3 = w[ch*9+3], w4 = w[ch*9+4];
  float w5 = w[ch*9+5], w6 = w[ch*9+6], w7 = w[ch*9+7], w8 = w[ch*9+8];
  float bv = wbias[ch];
  float vloc[16];
  float mx = -1e30f;
  #pragma unroll
  for (int j = 0; j < 16; j++){
    int p = tid + j * 256; int y = p >> 6, xx = p & 63;
    const float* r0 = &t[y * 66 + xx];
    float v = r0[0]*w0 + r0[1]*w1 + r0[2]*w2 + r0[66]*w3 + r0[67]*w4 + r0[68]*w5
            + r0[132]*w6 + r0[133]*w7 + r0[134]*w8 + bv;
    unsigned short h = f2b(v);
    op[p] = h;
    float vb = b2f(h);
    vloc[j] = vb;
    mx = fmaxf(mx, vb);
  }
  if (ch >= 128){                                    // dt channel: softmax stats
    #pragma unroll
    for (int off = 32; off > 0; off >>= 1) mx = fmaxf(mx, __shfl_down(mx, off));
    if ((tid & 63) == 0) red[tid >> 6] = mx;
    __syncthreads();
    float M = fmaxf(fmaxf(red[0], red[1]), fmaxf(red[2], red[3]));
    float se = 0.f;
    #pragma unroll
    for (int j = 0; j < 16; j++) se += __expf(vloc[j] - M);
    #pragma unroll
    for (int off = 32; off > 0; off >>= 1) se += __shfl_down(se, off);
    if ((tid & 63) == 0) red[4 + (tid >> 6)] = se;
    __syncthreads();
    if (tid == 0){
      smmax[b * 64 + ch - 128] = M;
      smsum[b * 64 + ch - 128] = red[4] + red[5] + red[6] + red[7];
    }
  }
}

// K5: AB = softmax(dt) * Bm  (bf16)
__global__ __launch_bounds__(256) void k_ab(
    const unsigned short* __restrict__ bc, const float* __restrict__ smmax,
    const float* __restrict__ smsum, unsigned short* __restrict__ ab){
  int blk = blockIdx.x; int b = blk >> 6, s = blk & 63;
  const unsigned short* dt = bc + ((size_t)(b * 192 + 128 + s)) * 4096;
  const unsigned short* bm = bc + ((size_t)(b * 192 + s)) * 4096;
  unsigned short* o = ab + ((size_t)(b * 64 + s)) * 4096;
  float M = smmax[b * 64 + s];
  float inv = 1.f / smsum[b * 64 + s];
  for (int i = threadIdx.x; i < 4096; i += 256)
    o[i] = f2b(__expf(b2f(dt[i]) - M) * inv * b2f(bm[i]));
}

// K5b: CmT (b,l,s) bf16 <- Cm channels 64..127 (tile transpose via LDS)
__global__ __launch_bounds__(256) void k_cmt(
    const unsigned short* __restrict__ bc, unsigned short* __restrict__ cmt){
  __shared__ float t[64 * 65];
  int blk = blockIdx.x; int b = blk >> 6, lt = blk & 63; int l0 = lt * 64;
  int tid = threadIdx.x;
  #pragma unroll
  for (int it = 0; it < 2; it++){
    int row = (tid >> 3) + it * 32;                  // s
    int lq = (tid & 7) * 8;
    const unsigned short* p = bc + ((size_t)(b * 192 + 64 + row)) * 4096 + l0 + lq;
    unsigned short vv[8];
    *reinterpret_cast<uint4*>(vv) = *reinterpret_cast<const uint4*>(p);
    #pragma unroll
    for (int k = 0; k < 8; k++) t[row * 65 + lq + k] = b2f(vv[k]);
  }
  __syncthreads();
  #pragma unroll
  for (int it = 0; it < 2; it++){
    int l = (tid >> 3) + it * 32;
    int sq = (tid & 7) * 8;
    unsigned short vv[8];
    #pragma unroll
    for (int k = 0; k < 8; k++) vv[k] = f2b(t[(sq + k) * 65 + l]);
    *reinterpret_cast<uint4*>(&cmt[((size_t)(b * 4096 + l0 + l)) * 64 + sq]) =
        *reinterpret_cast<uint4*>(vv);
  }
}

// ---------------------------------------------------------------------------
// K6: hT[b,s,c] += sum_l AB[s,l]*xf[c,l]  -- k-split over l, partials in ws
__global__ __launch_bounds__(512) void k_h(
    const unsigned short* __restrict__ ab, const unsigned short* __restrict__ xf,
    float* __restrict__ hpart){
  int blk = blockIdx.x; int b = blk & 15, chunk = blk >> 4;   // grid 128
  int t = threadIdx.x; int wv = t >> 6, lane = t & 63;
  int col = lane & 15, g = lane >> 4;
  int mt = wv & 3, nh = wv >> 2;
  f32x4 acc[8];
  #pragma unroll
  for (int nn = 0; nn < 8; nn++) acc[nn] = zero4();
  int lbase = chunk * 512;
  const unsigned short* ap = ab + ((size_t)(b * 64 + mt * 16 + col)) * 4096 + lbase + g * 8;
  for (int ks = 0; ks < 16; ks++){
    bf16x8 av = ldb8g(ap + ks * 32);
    #pragma unroll
    for (int nn = 0; nn < 8; nn++){
      int c = nh * 128 + nn * 16 + col;
      bf16x8 bv = ldb8g(&xf[((size_t)(b * 256 + c)) * 4096 + lbase + ks * 32 + g * 8]);
      acc[nn] = mfma16(av, bv, acc[nn]);
    }
  }
  #pragma unroll
  for (int nn = 0; nn < 8; nn++)
    #pragma unroll
    for (int r = 0; r < 4; r++){
      int s = mt * 16 + g * 4 + r;
      int c = nh * 128 + nn * 16 + col;
      hpart[(((size_t)chunk * 16 + b) * 64 + s) * 256 + c] = acc[nn][r];
    }
}

// K7pre: sum 8 k-partials
__global__ __launch_bounds__(256) void k_hsum(
    const float* __restrict__ hp, float* __restrict__ hs){
  int i = blockIdx.x * 256 + threadIdx.x;            // 262144
  float s = 0.f;
  #pragma unroll
  for (int c = 0; c < 8; c++) s += hp[(size_t)c * 262144 + i];
  hs[i] = s;
}

// K7a: u = hz_w @ h + hz_b ; hh1 = u_lo * (silu(u_hi) + D)   layout (b,s,o)
__global__ __launch_bounds__(256) void k_hz(
    const float* __restrict__ hs, const float* __restrict__ hzwT,
    const float* __restrict__ hzb, const float* __restrict__ Dp,
    float* __restrict__ hh1){
  __shared__ float ht[256][16];
  int blk = blockIdx.x; int b = blk >> 2, sc = blk & 3; int s0 = sc * 16;
  int t = threadIdx.x;
  {
    int si = t >> 4, c0 = (t & 15) * 16;
    const float* p = hs + ((size_t)(b * 64 + s0 + si)) * 256 + c0;
    #pragma unroll
    for (int k = 0; k < 16; k++) ht[c0 + k][si] = p[k];
  }
  __syncthreads();
  float Dv = Dp[0];
  float acc1[16], acc2[16];
  #pragma unroll
  for (int j = 0; j < 16; j++){ acc1[j] = 0.f; acc2[j] = 0.f; }
  for (int c = 0; c < 256; c++){
    float w1 = hzwT[c * 512 + t];
    float w2 = hzwT[c * 512 + 256 + t];
    float4 h0 = *reinterpret_cast<const float4*>(&ht[c][0]);
    float4 h1 = *reinterpret_cast<const float4*>(&ht[c][4]);
    float4 h2 = *reinterpret_cast<const float4*>(&ht[c][8]);
    float4 h3 = *reinterpret_cast<const float4*>(&ht[c][12]);
    float hv[16] = {h0.x,h0.y,h0.z,h0.w, h1.x,h1.y,h1.z,h1.w,
                    h2.x,h2.y,h2.z,h2.w, h3.x,h3.y,h3.z,h3.w};
    #pragma unroll
    for (int j = 0; j < 16; j++){ acc1[j] += w1 * hv[j]; acc2[j] += w2 * hv[j]; }
  }
  float bz1 = hzb[t], bz2 = hzb[256 + t];
  #pragma unroll
  for (int j = 0; j < 16; j++){
    float u = acc1[j] + bz1, z = acc2[j] + bz2;
    float sl = z / (1.f + __expf(-z));
    hh1[((size_t)(b * 64 + s0 + j)) * 256 + t] = u * (sl + Dv);
  }
}

// K7b: hh2 = out_w @ hh1 + out_b   -> bf16 (b,d,s)
__global__ __launch_bounds__(256) void k_out(
    const float* __restrict__ hh1, const float* __restrict__ outwT,
    const float* __restrict__ ob, unsigned short* __restrict__ hh2){
  __shared__ float ht[256][16];
  int blk = blockIdx.x; int b = blk >> 2, sc = blk & 3; int s0 = sc * 16;
  int t = threadIdx.x;
  {
    int si = t >> 4, o0 = (t & 15) * 16;
    const float* p = hh1 + ((size_t)(b * 64 + s0 + si)) * 256 + o0;
    #pragma unroll
    for (int k = 0; k < 16; k++) ht[o0 + k][si] = p[k];
  }
  __syncthreads();
  float acc[16];
  #pragma unroll
  for (int j = 0; j < 16; j++) acc[j] = 0.f;
  for (int o = 0; o < 256; o++){
    float w = outwT[o * 256 + t];
    float4 h0 = *reinterpret_cast<const float4*>(&ht[o][0]);
    float4 h1 = *reinterpret_cast<const float4*>(&ht[o][4]);
    float4 h2 = *reinterpret_cast<const float4*>(&ht[o][8]);
    float4 h3 = *reinterpret_cast<const float4*>(&ht[o][12]);
    float hv[16] = {h0.x,h0.y,h0.z,h0.w, h1.x,h1.y,h1.z,h1.w,
                    h2.x,h2.y,h2.z,h2.w, h3.x,h3.y,h3.z,h3.w};
    #pragma unroll
    for (int j = 0; j < 16; j++) acc[j] += w * hv[j];
  }
  float bo = ob[t];
  #pragma unroll
  for (int j = 0; j < 16; j++)
    hh2[((size_t)(b * 256 + t)) * 64 + s0 + j] = f2b(acc[j] + bo);
}

// K8: y = hh2 @ Cm ; x2 = (1-a1)*x1 + a1*y  (in-place on d_out)
__global__ __launch_bounds__(256) void k_y_blend(
    const unsigned short* __restrict__ hh2, const unsigned short* __restrict__ cmt,
    const float* __restrict__ alpha, float* __restrict__ x){
  int blk = blockIdx.x; int b = blk >> 6, lt = blk & 63; int l0 = lt * 64;
  int t = threadIdx.x; int wv = t >> 6, lane = t & 63;
  int col = lane & 15, g = lane >> 4;
  f32x4 acc[4][4];
  #pragma unroll
  for (int mm = 0; mm < 4; mm++)
    #pragma unroll
    for (int nn = 0; nn < 4; nn++) acc[mm][nn] = zero4();
  #pragma unroll
  for (int k = 0; k < 2; k++){
    bf16x8 av[4], bv[4];
    #pragma unroll
    for (int mm = 0; mm < 4; mm++){
      int c = (wv * 4 + mm) * 16 + col;
      av[mm] = ldb8g(&hh2[((size_t)(b * 256 + c)) * 64 + k * 32 + g * 8]);
    }
    #pragma unroll
    for (int nn = 0; nn < 4; nn++){
      int l = l0 + nn * 16 + col;
      bv[nn] = ldb8g(&cmt[((size_t)(b * 4096 + l)) * 64 + k * 32 + g * 8]);
    }
    #pragma unroll
    for (int mm = 0; mm < 4; mm++)
      #pragma unroll
      for (int nn = 0; nn < 4; nn++) acc[mm][nn] = mfma16(av[mm], bv[nn], acc[mm][nn]);
  }
  #pragma unroll
  for (int mm = 0; mm < 4; mm++)
    #pragma unroll
    for (int r = 0; r < 4; r++){
      int c = (wv * 4 + mm) * 16 + g * 4 + r;
      float a1 = sigm(alpha[c]);
      #pragma unroll
      for (int nn = 0; nn < 4; nn++){
        int l = l0 + nn * 16 + col;
        size_t idx = ((size_t)(b * 256 + c)) * 4096 + l;
        float xv = x[idx];
        x[idx] = (1.f - a1) * xv + a1 * acc[mm][nn][r];
      }
    }
}

// ---------------------------------------------------------------------------
// K11: fused FFN: out = (1-a3)*x3 + a3*(W2 @ gelu(W1 @ x3 + b1) + b2), in-place
// 64-pixel tile, 512 threads, XT+HT = 66KB LDS -> 2 blocks/CU. X fragments
// staged from pre-transposed x3T; stage-2 accumulators persist across the 4
// o-quarters.
__global__ __launch_bounds__(512, 4) void k_ffn(
    float* __restrict__ x, const unsigned short* __restrict__ xT,
    const unsigned short* __restrict__ w1b, const unsigned short* __restrict__ w2b,
    const float* __restrict__ b1, const float* __restrict__ b2,
    const float* __restrict__ alpha3){
  __shared__ unsigned short XT[64 * 264];
  __shared__ unsigned short HT[64 * 264];
  int blk = blockIdx.x; int b = blk >> 6, lt = blk & 63; int l0 = lt * 64;
  int t = threadIdx.x, wv = t >> 6, lane = t & 63;
  int col = lane & 15, g = lane >> 4;
  // stage XT (bf16, already transposed in global)
  #pragma unroll
  for (int it = 0; it < 4; it++){
    int idx = t + it * 512;                          // 2048 uint4 = 64 rows x 32
    int row = idx >> 5, cc = idx & 31;
    *reinterpret_cast<uint4*>(&XT[row * 264 + cc * 8]) =
        *reinterpret_cast<const uint4*>(&xT[((size_t)(b * 4096 + l0 + row)) * 256 + cc * 8]);
  }
  __syncthreads();
  f32x4 acc2[2][4];
  #pragma unroll
  for (int i = 0; i < 2; i++)
    #pragma unroll
    for (int nn = 0; nn < 4; nn++) acc2[i][nn] = zero4();
  for (int q = 0; q < 4; q++){
    int obq = q * 256;
    f32x4 acc1[2][4];
    #pragma unroll
    for (int i = 0; i < 2; i++)
      #pragma unroll
      for (int nn = 0; nn < 4; nn++) acc1[i][nn] = zero4();
    for (int k = 0; k < 8; k++){
      bf16x8 bv[4];
      #pragma unroll
      for (int nn = 0; nn < 4; nn++)
        bv[nn] = *reinterpret_cast<const bf16x8*>(&XT[(nn * 16 + col) * 264 + k * 32 + g * 8]);
      #pragma unroll
      for (int i = 0; i < 2; i++){
        int o = obq + (wv * 2 + i) * 16 + col;
        bf16x8 av = ldb8g(&w1b[(size_t)o * 256 + k * 32 + g * 8]);
        #pragma unroll
        for (int nn = 0; nn < 4; nn++) acc1[i][nn] = mfma16(av, bv[nn], acc1[i][nn]);
      }
    }
    __syncthreads();                                 // prev q's stage-2 reads done
    // gelu + write HT (bf16, [l][o_quarter])
    #pragma unroll
    for (int i = 0; i < 2; i++){
      int orow0 = (wv * 2 + i) * 16 + g * 4;
      #pragma unroll
      for (int nn = 0; nn < 4; nn++){
        int l = nn * 16 + col;
        unsigned short hv[4];
        #pragma unroll
        for (int r = 0; r < 4; r++){
          float u = acc1[i][nn][r] + b1[obq + orow0 + r];
          hv[r] = f2b(gelu_tanh(u));
        }
        *reinterpret_cast<uint2*>(&HT[l * 264 + orow0]) = *reinterpret_cast<uint2*>(hv);
      }
    }
    __syncthreads();
    for (int k = 0; k < 8; k++){
      bf16x8 bv[4];
      #pragma unroll
      for (int nn = 0; nn < 4; nn++)
        bv[nn] = *reinterpret_cast<const bf16x8*>(&HT[(nn * 16 + col) * 264 + k * 32 + g * 8]);
      #pragma unroll
      for (int i = 0; i < 2; i++){
        int d = (wv * 2 + i) * 16 + col;
        bf16x8 av = ldb8g(&w2b[(size_t)d * 1024 + obq + k * 32 + g * 8]);
        #pragma unroll
        for (int nn = 0; nn < 4; nn++) acc2[i][nn] = mfma16(av, bv[nn], acc2[i][nn]);
      }
    }
  }
  #pragma unroll
  for (int i = 0; i < 2; i++)
    #pragma unroll
    for (int nn = 0; nn < 4; nn++)
      #pragma unroll
      for (int r = 0; r < 4; r++){
        int d = (wv * 2 + i) * 16 + g * 4 + r;
        int l = l0 + nn * 16 + col;
        float a3 = sigm(alpha3[d]);
        size_t idx = ((size_t)(b * 256 + d)) * 4096 + l;
        float xv = x[idx];
        x[idx] = (1.f - a3) * xv + a3 * (acc2[i][nn][r] + b2[d]);
      }
}

// ---------------------------------------------------------------------------
extern "C" void kernel_launch(void* const* d_in, const int* in_sizes, int n_in,
                              void* d_out, int out_size, void* d_ws, size_t ws_size,
                              hipStream_t stream){
  (void)in_sizes; (void)n_in; (void)out_size; (void)ws_size;
  const float* x      = (const float*)d_in[0];
  const float* alpha  = (const float*)d_in[1];
  const float* dw1_w  = (const float*)d_in[2];
  const float* bn1_g  = (const float*)d_in[3];
  const float* bn1_b  = (const float*)d_in[4];
  const float* dw2_w  = (const float*)d_in[5];
  const float* bn2_g  = (const float*)d_in[6];
  const float* bn2_b  = (const float*)d_in[7];
  const float* ln_w   = (const float*)d_in[8];
  const float* ln_b   = (const float*)d_in[9];
  const float* bcdt_w = (const float*)d_in[10];
  const float* bcdt_b = (const float*)d_in[11];
  const float* mdw_w  = (const float*)d_in[12];
  const float* mdw_b  = (const float*)d_in[13];
  const float* hz_w   = (const float*)d_in[14];
  const float* hz_b   = (const float*)d_in[15];
  const float* out_w  = (const float*)d_in[16];
  const float* out_b  = (const float*)d_in[17];
  // d_in[18] = A: cancels exactly in softmax over L (constant shift per row)
  const float* Dvec   = (const float*)d_in[19];
  const float* ffn_w1 = (const float*)d_in[20];
  const float* ffn_b1 = (const float*)d_in[21];
  const float* ffn_w2 = (const float*)d_in[22];
  const float* ffn_b2 = (const float*)d_in[23];
  float* out = (float*)d_out;
  char* ws = (char*)d_ws;

  const size_t OFF_BCRAW = 0;                    // 16*192*4096*2 = 25165824
  const size_t OFF_BCC   = 25165824;             // 25165824
  const size_t OFF_XF    = 50331648;             // 33554432 (reused as x3T later)
  const size_t OFF_XFT   = 83886080;             // 33554432
  const size_t OFF_AB    = 117440512;            // 8388608
  const size_t OFF_CMT   = 125829120;            // 8388608
  const size_t OFF_HPART = 134217728;            // 8388608
  const size_t OFF_HS    = 142606336;            // 1048576
  const size_t OFF_HH1   = 143654912;            // 1048576
  const size_t OFF_HH2   = 144703488;            // 524288
  const size_t OFF_W1B   = 145227776;            // 524288
  const size_t OFF_W2B   = 145752064;            // 524288
  const size_t OFF_BWB   = 146276352;            // 98304
  const size_t OFF_HZWT  = 146374656;            // 524288
  const size_t OFF_OUTWT = 146898944;            // 262144
  const size_t OFF_STATS = 147161088;            // 4096: bn1sum,bn1sq,bn2sum,bn2sq
  const size_t OFF_SMMAX = 147165184;            // 4096
  const size_t OFF_SMSUM = 147169280;            // 4096

  unsigned short* bcraw = (unsigned short*)(ws + OFF_BCRAW);
  unsigned short* bcc   = (unsigned short*)(ws + OFF_BCC);
  unsigned short* xf    = (unsigned short*)(ws + OFF_XF);
  unsigned short* xfT   = (unsigned short*)(ws + OFF_XFT);
  unsigned short* x3T   = (unsigned short*)(ws + OFF_XF);   // reuse (xf dead)
  unsigned short* ab    = (unsigned short*)(ws + OFF_AB);
  unsigned short* cmt   = (unsigned short*)(ws + OFF_CMT);
  float* hpart = (float*)(ws + OFF_HPART);
  float* hs    = (float*)(ws + OFF_HS);
  float* hh1   = (float*)(ws + OFF_HH1);
  unsigned short* hh2 = (unsigned short*)(ws + OFF_HH2);
  unsigned short* w1b = (unsigned short*)(ws + OFF_W1B);
  unsigned short* w2b = (unsigned short*)(ws + OFF_W2B);
  unsigned short* bwb = (unsigned short*)(ws + OFF_BWB);
  float* hzwT  = (float*)(ws + OFF_HZWT);
  float* outwT = (float*)(ws + OFF_OUTWT);
  float* bn1sum = (float*)(ws + OFF_STATS);
  float* bn1sq  = bn1sum + 256;
  float* bn2sum = bn1sum + 512;
  float* bn2sq  = bn1sum + 768;
  float* smmax = (float*)(ws + OFF_SMMAX);
  float* smsum = (float*)(ws + OFF_SMSUM);

  hipMemsetAsync(ws + OFF_STATS, 0, 4096, stream);
  k_setup<<<1024, 256, 0, stream>>>(ffn_w1, ffn_w2, bcdt_w, hz_w, out_w,
                                    w1b, w2b, bwb, hzwT, outwT);
  // stage 1: x1 = blend(x, BN(conv(x))), into d_out
  k_conv_stats<<<4096, 256, 0, stream>>>(x, dw1_w, bn1sum, bn1sq);
  k_conv_bn_blend<<<4096, 256, 0, stream>>>(x, dw1_w, bn1sum, bn1sq,
                                            bn1_g, bn1_b, alpha + 0, out);
  // LN -> xf/xfT bf16
  k_ln<<<1024, 256, 0, stream>>>(out, ln_w, ln_b, xf, xfT);
  // mixer
  k_bcdt<<<1024, 256, 0, stream>>>(xfT, bwb, bcdt_b, bcraw);
  k_conv_mid<<<3072, 256, 0, stream>>>(bcraw, mdw_w, mdw_b, bcc, smmax, smsum);
  k_ab<<<1024, 256, 0, stream>>>(bcc, smmax, smsum, ab);
  k_cmt<<<1024, 256, 0, stream>>>(bcc, cmt);
  k_h<<<128, 512, 0, stream>>>(ab, xf, hpart);
  k_hsum<<<1024, 256, 0, stream>>>(hpart, hs);
  k_hz<<<64, 256, 0, stream>>>(hs, hzwT, hz_b, Dvec, hh1);
  k_out<<<64, 256, 0, stream>>>(hh1, outwT, out_b, hh2);
  k_y_blend<<<1024, 256, 0, stream>>>(hh2, cmt, alpha + 256, out);
  // stage 2: x3 = blend(x2, BN2(conv2(x2))), in-place on d_out
  k_conv_stats<<<4096, 256, 0, stream>>>(out, dw2_w, bn2sum, bn2sq);
  k_conv_bn_blend<<<4096, 256, 0, stream>>>(out, dw2_w, bn2sum, bn2sq,
                                            bn2_g, bn2_b, alpha + 512, out);
  // x3 -> x3T bf16 (xf region is dead by now)
  k_xt<<<1024, 256, 0, stream>>>(out, x3T);
  // fused FFN + final blend, in-place on d_out
  k_ffn<<<1024, 512, 0, stream>>>(out, x3T, w1b, w2b, ffn_b1, ffn_b2, alpha + 768);
}